// Round 4
// baseline (436.412 us; speedup 1.0000x reference)
//
#include <hip/hip_runtime.h>

#define NUM_NODES 10000
#define TOP_K 5

// ---------------------------------------------------------------------------
// Streaming top-5 via 5 u64 slots/node + cascading atomicMin.
//
// key  = score_bits(32) | (0x7FFFF - i)(19) | e(13)   (score>0 -> bit order ==
//        value order; i<2^19 unique -> u64 order == (score desc, idx asc);
//        e rides along for free decode)
// inv  = ~key  -> top-5 largest keys == 5 SMALLEST inv values.
// slots init = 0xFF..FF (+inf for atomicMin), via a 400 KB memset node.
//
// Cascade insert (per candidate): for j=0..4 { old = atomicMin(&s[j], val);
// val = max(old, val); }. Each atomicMin atomically swaps carried<->slot or
// passes; the value multiset is conserved, slot values are monotone
// non-increasing, and a value dropped off the end certifies 5 distinct
// smaller inserted values -> final slots are exactly the 5 smallest.
//
// Pre-filter: if (inv > s[4] plain-load) skip the cascade. Safe under
// staleness/non-coherent L2: slots only decrease, so any historical s[4]
// value w < inv certifies 5 distinct inserted values <= w < inv existed
// at that time -> inv can never be top-5. Expected cascades ~5*ln(deg/5)
// ~= 10 per node vs deg ~= 39 candidates.
// ---------------------------------------------------------------------------
__global__ void k_score(const int* __restrict__ edge,
                        const float* __restrict__ logits,
                        float* __restrict__ out,
                        unsigned long long* __restrict__ slots,
                        int nnz, int num_edges) {
    int i = blockIdx.x * blockDim.x + threadIdx.x;
    if (i >= nnz) return;
    int v = edge[i];
    int e = edge[nnz + i];
    float x = logits[(long long)v * num_edges + e];
    float s = 1.0f / (1.0f + expf(-x));   // keep bit-identical to passing rounds
    out[i]           = -1.0f;             // default: dropped
    out[nnz + i]     = -1.0f;
    out[2 * nnz + i] = s;

    unsigned long long key =
        ((unsigned long long)__float_as_uint(s) << 32) |
        ((unsigned long long)(0x7FFFFu - (unsigned int)i) << 13) |
        (unsigned long long)(unsigned int)e;
    unsigned long long inv = ~key;        // key!=0 always (i<2^19-1), so inv!=~0

    unsigned long long* sl = slots + (long long)v * TOP_K;
    if (inv < sl[TOP_K - 1]) {            // pre-filter (stale-larger is safe)
        unsigned long long val = inv;
        #pragma unroll
        for (int j = 0; j < TOP_K; j++) {
            unsigned long long old = atomicMin(&sl[j], val);
            val = (old > val) ? old : val;          // carry the displaced max
            if (val == 0xFFFFFFFFFFFFFFFFull) break; // displaced an empty slot
        }
    }
}

// ---------------------------------------------------------------------------
// One thread per (node, slot): decode winners, write kept (v, e) pairs.
// Untouched slots are still 0xFF..FF; real inv can never equal ~0
// (key==0 would need i==0x7FFFF > nnz).
// ---------------------------------------------------------------------------
__global__ void k_tail(const unsigned long long* __restrict__ slots,
                       float* __restrict__ out, int nnz) {
    int t = blockIdx.x * blockDim.x + threadIdx.x;
    if (t >= NUM_NODES * TOP_K) return;
    unsigned long long inv = slots[t];
    if (inv == 0xFFFFFFFFFFFFFFFFull) return;
    unsigned long long key = ~inv;
    int e = (int)(key & 0x1FFFull);
    int i = 0x7FFFF - (int)((key >> 13) & 0x7FFFFull);
    int v = t / TOP_K;
    out[i]       = (float)v;
    out[nnz + i] = (float)e;
}

// ---------------------------------------------------------------------------
extern "C" void kernel_launch(void* const* d_in, const int* in_sizes, int n_in,
                              void* d_out, int out_size, void* d_ws, size_t ws_size,
                              hipStream_t stream) {
    const int*   edge   = (const int*)d_in[0];
    const float* logits = (const float*)d_in[1];
    float*       out    = (float*)d_out;
    int nnz       = in_sizes[0] / 2;
    int num_edges = in_sizes[1] / NUM_NODES;

    unsigned long long* slots = (unsigned long long*)d_ws;  // 400 KB

    hipMemsetAsync(slots, 0xFF, (size_t)NUM_NODES * TOP_K * sizeof(unsigned long long), stream);
    k_score<<<(nnz + 255) / 256,              256, 0, stream>>>(edge, logits, out, slots, nnz, num_edges);
    k_tail <<<(NUM_NODES * TOP_K + 255) / 256, 256, 0, stream>>>(slots, out, nnz);
}

// Round 5
// 390.628 us; speedup vs baseline: 1.1172x; 1.1172x over previous
//
#include <hip/hip_runtime.h>

#define NUM_NODES 10000
#define TOP_K 5
#define CAP 128   // per-node bucket capacity; deg ~ Binomial(320000, 1/8192), lambda=39,
                  // P(any node > 128) ~ e^-63 — clamped/guarded regardless.

// ---------------------------------------------------------------------------
// K1: scores + bucket scatter of fully-packed keys, 2 incidences per thread.
// key = score_bits(32) | (0x7FFFF - i)(19) | e(13)
//   - score = sigmoid in (0,1) -> positive float -> bit order == value order
//   - i < 320000 < 2^19 unique -> u64 order == (score desc, idx asc)  [ref tie-break]
//   - e < 8192 = 2^13 rides along for free decode; never affects ordering
//   - key 0 is a safe sentinel (score bits always > 0)
// bucket node-major: bucket[v*CAP + pos]; out rows 0/1 pre-filled to -1.0f
// by a memset node (0xBF800000), so K1 only writes scores.
// ---------------------------------------------------------------------------
__global__ void k_score(const int* __restrict__ edge,
                        const float* __restrict__ logits,
                        float* __restrict__ out,
                        int* __restrict__ cnt,
                        unsigned long long* __restrict__ bucket,
                        int nnz, int num_edges) {
    int j = blockIdx.x * blockDim.x + threadIdx.x;   // pair index
    int npair = nnz >> 1;
    if (j >= npair) return;

    int2 vv = ((const int2*)edge)[j];                // row0: node ids (8B coalesced)
    int2 ee = ((const int2*)(edge + nnz))[j];        // row1: hyperedge ids

    // two independent random gathers in flight
    float x0 = logits[(long long)vv.x * num_edges + ee.x];
    float x1 = logits[(long long)vv.y * num_edges + ee.y];
    float s0 = 1.0f / (1.0f + expf(-x0));            // bit-identical to passing rounds
    float s1 = 1.0f / (1.0f + expf(-x1));

    ((float2*)(out + 2 * nnz))[j] = make_float2(s0, s1);

    unsigned int i0 = 2u * (unsigned int)j, i1 = i0 + 1u;
    unsigned long long key0 =
        ((unsigned long long)__float_as_uint(s0) << 32) |
        ((unsigned long long)(0x7FFFFu - i0) << 13) |
        (unsigned long long)(unsigned int)ee.x;
    unsigned long long key1 =
        ((unsigned long long)__float_as_uint(s1) << 32) |
        ((unsigned long long)(0x7FFFFu - i1) << 13) |
        (unsigned long long)(unsigned int)ee.y;

    int p0 = atomicAdd(&cnt[vv.x], 1);
    if (p0 < CAP) bucket[(long long)vv.x * CAP + p0] = key0;
    int p1 = atomicAdd(&cnt[vv.y], 1);
    if (p1 < CAP) bucket[(long long)vv.y * CAP + p1] = key1;
}

// ---------------------------------------------------------------------------
// K2: ONE WAVE PER NODE. Lane j holds slots j and j+64 (coalesced, predicated:
// n~39 so the second load is usually skipped), 5 rounds of 64-lane butterfly
// max; owner lane clears its copy; lane 0 decodes (i, e) from the key and
// writes the kept pair. Everything else stays -1 from the memset node.
// ---------------------------------------------------------------------------
__global__ void k_topk(const int* __restrict__ cnt,
                       const unsigned long long* __restrict__ bucket,
                       float* __restrict__ out, int nnz) {
    int wave = threadIdx.x >> 6;                 // 4 waves per block
    int lane = threadIdx.x & 63;
    int v = blockIdx.x * 4 + wave;
    if (v >= NUM_NODES) return;
    int n = cnt[v];
    if (n > CAP) n = CAP;
    if (n <= 0) return;

    const unsigned long long* b = bucket + (long long)v * CAP;
    unsigned long long k0 = (lane      < n) ? b[lane]      : 0ull;
    unsigned long long k1 = (lane + 64 < n) ? b[lane + 64] : 0ull;

    #pragma unroll
    for (int t = 0; t < TOP_K; t++) {
        unsigned long long m = (k0 > k1) ? k0 : k1;
        #pragma unroll
        for (int d = 32; d >= 1; d >>= 1) {
            unsigned long long o = __shfl_xor(m, d, 64);
            m = (o > m) ? o : m;
        }
        if (m == 0ull) break;                    // wave-uniform after reduction
        k0 = (k0 == m) ? 0ull : k0;              // clear the winner's copy
        k1 = (k1 == m) ? 0ull : k1;
        if (lane == 0) {
            int e = (int)(m & 0x1FFFull);
            int i = 0x7FFFF - (int)((m >> 13) & 0x7FFFFull);
            out[i]       = (float)v;
            out[nnz + i] = (float)e;
        }
    }
}

// ---------------------------------------------------------------------------
extern "C" void kernel_launch(void* const* d_in, const int* in_sizes, int n_in,
                              void* d_out, int out_size, void* d_ws, size_t ws_size,
                              hipStream_t stream) {
    const int*   edge   = (const int*)d_in[0];
    const float* logits = (const float*)d_in[1];
    float*       out    = (float*)d_out;
    int nnz       = in_sizes[0] / 2;
    int num_edges = in_sizes[1] / NUM_NODES;

    // ws layout: bucket[NUM_NODES*CAP] u64 (8B-aligned first), then cnt[NUM_NODES] int
    unsigned long long* bucket = (unsigned long long*)d_ws;
    int* cnt = (int*)(bucket + (size_t)NUM_NODES * CAP);

    hipMemsetAsync(cnt, 0, NUM_NODES * sizeof(int), stream);
    // pruned_edge_index rows default to -1.0f (bit pattern 0xBF800000)
    hipMemsetD32Async((hipDeviceptr_t)out, (int)0xBF800000, (size_t)(2 * nnz), stream);

    k_score<<<((nnz / 2) + 255) / 256, 256, 0, stream>>>(edge, logits, out, cnt, bucket, nnz, num_edges);
    k_topk <<<(NUM_NODES + 3) / 4,     256, 0, stream>>>(cnt, bucket, out, nnz);
}